// Round 4
// baseline (89.585 us; speedup 1.0000x reference)
//
#include <hip/hip_runtime.h>
#include <math.h>

#define N      4096
#define BLOCK  256                 // one j per thread
#define ISEG   64                  // i-rows per block (2 x 32 segments)
#define NJT    (N / BLOCK)         // 16 j-tiles
#define NTILE  544                 // sum_{J=0..15} (4J+4) = 2*16*17

// s(e) = sum_k 1/(1 + c_k*e), c_k = e^{-t_k}, t = {0.5,1,2,4} = Pn(e)/Pd(e)
#define PN0 4.0f
#define PN1 3.384183069f
#define PN2 0.750655861f
#define PN3 0.036699475f
#define PD1 1.128061023f
#define PD2 0.375327930f
#define PD3 0.036699475f
#define PD4 0.000553084f

__device__ __forceinline__ int tile_off(int J) { return 2 * J * (J + 1); }

// NOTE (prev session): no fused reduction via atomics+ticket (cost ~75us).
// NOTE (R1): depth-1 SW pipeline of LDS reads REGRESSED (+6.4us).
// NOTE (R2): removing ALL hot-loop LDS (j per-lane, i uniform via s_load)
// NEUTRAL. NOTE (R3): occupancy 4->8 waves/SIMD NEUTRAL (+1.7, noise).
// => hot-loop structure is NOT the limiter. Remaining controllable costs
// are per-block fixed overhead x block count, scheduling rounds/tail, and
// the finalize dispatch. This round: 64i x 256j tiles -> 1088 blocks total
// (was 2176), all resident in ONE round at 5 blk/CU (launch_bounds 256,5;
// VGPR cap ~96). Halved prologues/epilogues, no tail.
__global__ __launch_bounds__(BLOCK, 5) void lddt_main_kernel(
    const float* __restrict__ pred, const float* __restrict__ truec,
    const int* __restrict__ is_dna, const int* __restrict__ is_rna,
    const int* __restrict__ cmask, float* __restrict__ ws)
{
    const int L     = blockIdx.x;     // 0..NTILE-1, linear tile id
    const int batch = blockIdx.z;
    const int tid   = threadIdx.x;

    int J = 0;
#pragma unroll
    for (int u = 1; u < NJT; ++u) J += (L >= tile_off(u)) ? 1 : 0;
    const int S    = L - tile_off(J);        // i-block, in [0, 4J+4)
    const bool diag = (S >= 4 * J);          // i-range inside j-range
    const int i0   = S * ISEG;
    const int j0   = J * BLOCK;
    const int j    = j0 + tid;               // this thread's j (per-lane)

    const float* pb = pred  + (size_t)batch * N * 3;
    const float* tb = truec + (size_t)batch * N * 3;
    const int* dnab = is_dna + (size_t)batch * N;
    const int* rnab = is_rna + (size_t)batch * N;
    const int* cmb  = cmask  + (size_t)batch * N;

    // per-lane j-data, loaded once (coalesced)
    const float pjx = pb[j*3+0], pjy = pb[j*3+1], pjz = pb[j*3+2];
    const float tjx = tb[j*3+0], tjy = tb[j*3+1], tjz = tb[j*3+2];
    const float cutA = (dnab[j] | rnab[j]) ? 900.0f : 225.0f;  // 30^2 : 15^2
    const float cjw  = cmb[j] ? 1.0f : 0.0f;

    float num = 0.0f, den = 0.0f;

    // One i (uniform): i-row scalars come from SGPRs (s_load). cm_i/nuc_i
    // fold into cutl: cutl = -1 when cm_i==0 -> m=0.
#define IBODY(IDX, NEED_TRI, TT, NDOUT)                                        \
    {                                                                          \
        const int i = i0 + (IDX);                                              \
        const float six = pb[i*3+0], siy = pb[i*3+1], siz = pb[i*3+2];         \
        const float tix = tb[i*3+0], tiy = tb[i*3+1], tiz = tb[i*3+2];         \
        const bool nuci = (dnab[i] | rnab[i]) != 0;                            \
        const bool cmi  = cmb[i] != 0;                                         \
        float dxp = pjx - six, dyp = pjy - siy, dzp = pjz - siz;               \
        float d2p = dxp*dxp + dyp*dyp + dzp*dzp;                               \
        float dxt = tjx - tix, dyt = tjy - tiy, dzt = tjz - tiz;               \
        float d2t = dxt*dxt + dyt*dyt + dzt*dzt;                               \
        float dpv = __builtin_amdgcn_sqrtf(d2p);                               \
        float dtv = __builtin_amdgcn_sqrtf(d2t);                               \
        float e   = __expf(fminf(fabsf(dtv - dpv), 10.0f));                    \
        float NNv = ((e * PN3 + PN2) * e + PN1) * e + PN0;                     \
        NDOUT = (((e * PD4 + PD3) * e + PD2) * e + PD1) * e + 1.0f;            \
        float cutl = cmi ? (nuci ? cutA : 225.0f) : -1.0f;                     \
        bool k = d2t < cutl;                                                   \
        if (NEED_TRI) k = k && (j > i);                                        \
        float m = k ? cjw : 0.0f;                                              \
        den += m;                                                              \
        TT = m * NNv;                                                          \
    }

    // two i's per step share one rcp
#define ILOOP(NEED_TRI)                                                        \
    _Pragma("unroll 2")                                                        \
    for (int ii = 0; ii < ISEG; ii += 2) {                                     \
        float t0, t1, nd0, nd1;                                                \
        IBODY(ii,     NEED_TRI, t0, nd0)                                       \
        IBODY(ii + 1, NEED_TRI, t1, nd1)                                       \
        float na = fmaf(t0, nd1, t1 * nd0);                                    \
        num = fmaf(na, __builtin_amdgcn_rcpf(nd0 * nd1), num);                 \
    }

    if (diag) {
        ILOOP(true)
    } else {
        ILOOP(false)
    }
#undef ILOOP
#undef IBODY

    // symmetry x2, threshold-mean /4  (cm_i folded into cutl, cm_j in cjw)
    num *= 0.5f;
    den *= 2.0f;

    for (int off = 32; off > 0; off >>= 1) {
        num += __shfl_down(num, off);
        den += __shfl_down(den, off);
    }
    __shared__ float rn[BLOCK / 64], rd[BLOCK / 64];
    const int wid = tid >> 6, lane = tid & 63;
    if (lane == 0) { rn[wid] = num; rd[wid] = den; }
    __syncthreads();
    if (tid == 0) {
        float tn = rn[0] + rn[1] + rn[2] + rn[3];
        float td = rd[0] + rd[1] + rd[2] + rd[3];
        const int bid = batch * NTILE + L;
        ws[bid * 2 + 0] = tn;   // plain stores to distinct slots -> no init,
        ws[bid * 2 + 1] = td;   // no atomics, no fence
    }
}

// 1-wave finalize: no LDS, no barriers, float2 loads (9 iters/batch),
// shfl-only reduction.
__global__ __launch_bounds__(64) void finalize_kernel(
    const float* __restrict__ ws, float* __restrict__ out, int b)
{
    const int lane = threadIdx.x;
    float acc = 0.0f;
    for (int k = 0; k < b; ++k) {
        float n = 0.0f, d = 0.0f;
        const float2* w2 = (const float2*)(ws + (size_t)k * NTILE * 2);
        for (int p = lane; p < NTILE; p += 64) {
            float2 v = w2[p];
            n += v.x; d += v.y;
        }
        for (int off = 32; off > 0; off >>= 1) {
            n += __shfl_down(n, off);
            d += __shfl_down(d, off);
        }
        if (lane == 0) acc += n / fmaxf(d, 1.0f);
    }
    if (lane == 0) out[0] = 1.0f - acc / (float)b;
}

extern "C" void kernel_launch(void* const* d_in, const int* in_sizes, int n_in,
                              void* d_out, int out_size, void* d_ws, size_t ws_size,
                              hipStream_t stream) {
    const float* pred  = (const float*)d_in[0];
    const float* truec = (const float*)d_in[1];
    const int* is_dna  = (const int*)d_in[2];
    const int* is_rna  = (const int*)d_in[3];
    const int* cmask   = (const int*)d_in[4];
    float* out = (float*)d_out;
    float* ws  = (float*)d_ws;

    const int b = in_sizes[2] / N;

    dim3 grid(NTILE, 1, b);   // 544 x b = 1088 blocks, all resident at 5/CU
    lddt_main_kernel<<<grid, BLOCK, 0, stream>>>(pred, truec, is_dna, is_rna, cmask, ws);
    finalize_kernel<<<1, 64, 0, stream>>>(ws, out, b);
}

// Round 5
// 87.169 us; speedup vs baseline: 1.0277x; 1.0277x over previous
//
#include <hip/hip_runtime.h>
#include <math.h>

#define N      4096
#define BLOCK  256                 // one j per thread
#define ISEG   32                  // i-rows per block
#define NJT    (N / BLOCK)         // 16 j-tiles
#define NTILE  1088                // sum_{J=0..15} (8J+8) = 4*16*17

// s(e) = sum_k 1/(1 + c_k*e), c_k = e^{-t_k}, t = {0.5,1,2,4} = Pn(e)/Pd(e)
#define PN0 4.0f
#define PN1 3.384183069f
#define PN2 0.750655861f
#define PN3 0.036699475f
#define PD1 1.128061023f
#define PD2 0.375327930f
#define PD3 0.036699475f
#define PD4 0.000553084f

__device__ __forceinline__ int tile_off(int J) { return 4 * J * (J + 1); }

__device__ __forceinline__ float rdlane(float v, int l) {
    return __int_as_float(__builtin_amdgcn_readlane(__float_as_int(v), l));
}

// LEDGER:
// prev session: fused reduction via atomics+ticket -> ~75us regression.
// R1: depth-1 SW pipeline of LDS broadcast reads -> +6.4us (VGPR pressure).
// R2: j per-lane VGPR, i via s_load, zero hot-loop LDS -> NEUTRAL (82.5).
// R3: launch_bounds (256,8) -> neutral/noise (84.2). Occupancy not binding.
// R4: 64i x 256j, 1088 blocks, (256,5) -> +7us. Longer waves expose the
//     per-iteration stall; fewer blocks hide less. REVERTED.
// Diagnosis: R0 (ds_read bcast ~120cy) == R2 (s_load bcast ~200-300cy) ==
// ~82us total: hot loop sits behind a per-iteration broadcast MEMORY load
// the compiler won't pipeline deeply. THIS ROUND: no memory in the hot
// loop at all. Preload the block's 32 i-rows (7 floats each) into 7 VGPRs
// lane-indexed, fully unroll the i-loop, broadcast via v_readlane (imm
// lane, VALU pipe, 2cy, -> SGPR). Single-variable A/B vs R2.
__global__ __launch_bounds__(BLOCK, 4) void lddt_main_kernel(
    const float* __restrict__ pred, const float* __restrict__ truec,
    const int* __restrict__ is_dna, const int* __restrict__ is_rna,
    const int* __restrict__ cmask, float* __restrict__ ws)
{
    const int L     = blockIdx.x;     // 0..NTILE-1, linear tile id
    const int batch = blockIdx.z;
    const int tid   = threadIdx.x;

    int J = 0;
#pragma unroll
    for (int u = 1; u < NJT; ++u) J += (L >= tile_off(u)) ? 1 : 0;
    const int S    = L - tile_off(J);        // i-seg, in [0, 8J+8)
    const bool diag = (S >= 8 * J);          // i-range overlaps j-range
    const int i0   = S * ISEG;
    const int j0   = J * BLOCK;
    const int j    = j0 + tid;               // this thread's j (per-lane)

    const float* pb = pred  + (size_t)batch * N * 3;
    const float* tb = truec + (size_t)batch * N * 3;
    const int* dnab = is_dna + (size_t)batch * N;
    const int* rnab = is_rna + (size_t)batch * N;
    const int* cmb  = cmask  + (size_t)batch * N;

    // per-lane j-data, loaded once (coalesced)
    const float pjx = pb[j*3+0], pjy = pb[j*3+1], pjz = pb[j*3+2];
    const float tjx = tb[j*3+0], tjy = tb[j*3+1], tjz = tb[j*3+2];
    const float cutA = (dnab[j] | rnab[j]) ? 900.0f : 225.0f;  // 30^2 : 15^2
    const float cjw  = cmb[j] ? 1.0f : 0.0f;

    // i-row register file: lane l (l&31) carries row i0+(l&31).
    // 7 VGPRs; lanes 32-63 duplicate lanes 0-31 (readlane only reads 0-31).
    const int ip = i0 + (tid & 31);
    const float rpx = pb[ip*3+0], rpy = pb[ip*3+1], rpz = pb[ip*3+2];
    const float rtx = tb[ip*3+0], rty = tb[ip*3+1], rtz = tb[ip*3+2];
    // cm_i / nuc_i folded into one scalar cutoff (cutl=-1 -> mask 0)
    const float rcut = cmb[ip] ? ((dnab[ip] | rnab[ip]) ? cutA * 0.0f + ((dnab[ip] | rnab[ip]) ? 1.0f : 0.0f) * 0.0f + 900.0f : 225.0f) : -1.0f;
    // NOTE: rcut for pair (i,j) must still AND with nuc_j: nuc-cutoff 900
    // applies only when BOTH are nucleotide. Handle via two scalars:
    const float rnuc = (dnab[ip] | rnab[ip]) ? 1.0f : 0.0f;   // nuc_i
    const float rcm  = cmb[ip] ? 1.0f : 0.0f;                 // cm_i

    float num = 0.0f, den = 0.0f;

    // Per i (uniform, fully unrolled): 8 readlane broadcasts -> SGPRs,
    // then a pure-register body. cut = cm_i ? (nuc_i*nuc_j ? 900 : 225) : -1
    // expressed as: cutl = 225 + nuci*(cutA-225) gated by cmi, with
    // cutA per-lane (=900 if nuc_j else 225) -> nuc pair logic preserved.
#define IBODY(IDX, NEED_TRI, TT, NDOUT)                                        \
    {                                                                          \
        const int i = i0 + (IDX);                                              \
        const float six = rdlane(rpx, (IDX));                                  \
        const float siy = rdlane(rpy, (IDX));                                  \
        const float siz = rdlane(rpz, (IDX));                                  \
        const float tix = rdlane(rtx, (IDX));                                  \
        const float tiy = rdlane(rty, (IDX));                                  \
        const float tiz = rdlane(rtz, (IDX));                                  \
        const float nuci = rdlane(rnuc, (IDX));                                \
        const float cmi  = rdlane(rcm,  (IDX));                                \
        float dxp = pjx - six, dyp = pjy - siy, dzp = pjz - siz;               \
        float d2p = dxp*dxp + dyp*dyp + dzp*dzp;                               \
        float dxt = tjx - tix, dyt = tjy - tiy, dzt = tjz - tiz;               \
        float d2t = dxt*dxt + dyt*dyt + dzt*dzt;                               \
        float dpv = __builtin_amdgcn_sqrtf(d2p);                               \
        float dtv = __builtin_amdgcn_sqrtf(d2t);                               \
        float e   = __expf(fminf(fabsf(dtv - dpv), 10.0f));                    \
        float NNv = ((e * PN3 + PN2) * e + PN1) * e + PN0;                     \
        NDOUT = (((e * PD4 + PD3) * e + PD2) * e + PD1) * e + 1.0f;            \
        /* pair cutoff: both nuc -> 900 (cutA=900 iff nuc_j), else 225 */      \
        float cutl = fmaf(nuci, cutA - 225.0f, 225.0f);                        \
        bool k = (d2t < cutl) && (cmi > 0.0f);                                 \
        if (NEED_TRI) k = k && (j > i);                                        \
        float m = k ? cjw : 0.0f;                                              \
        den += m;                                                              \
        TT = m * NNv;                                                          \
    }

    // two i's per step share one rcp; FULL unroll -> readlane imm lane
#define ILOOP(NEED_TRI)                                                        \
    _Pragma("unroll")                                                          \
    for (int ii = 0; ii < ISEG; ii += 2) {                                     \
        float t0, t1, nd0, nd1;                                                \
        IBODY(ii,     NEED_TRI, t0, nd0)                                       \
        IBODY(ii + 1, NEED_TRI, t1, nd1)                                       \
        float na = fmaf(t0, nd1, t1 * nd0);                                    \
        num = fmaf(na, __builtin_amdgcn_rcpf(nd0 * nd1), num);                 \
    }

    if (diag) {
        ILOOP(true)
    } else {
        ILOOP(false)
    }
#undef ILOOP
#undef IBODY

    // symmetry x2, threshold-mean /4  (cm_i in k, cm_j in cjw)
    num *= 0.5f;
    den *= 2.0f;

    for (int off = 32; off > 0; off >>= 1) {
        num += __shfl_down(num, off);
        den += __shfl_down(den, off);
    }
    __shared__ float rn[BLOCK / 64], rd[BLOCK / 64];
    const int wid = tid >> 6, lane = tid & 63;
    if (lane == 0) { rn[wid] = num; rd[wid] = den; }
    __syncthreads();
    if (tid == 0) {
        float tn = rn[0] + rn[1] + rn[2] + rn[3];
        float td = rd[0] + rd[1] + rd[2] + rd[3];
        const int bid = batch * NTILE + L;
        ws[bid * 2 + 0] = tn;   // plain stores to distinct slots -> no init,
        ws[bid * 2 + 1] = td;   // no atomics, no fence
    }
}

// finalize: known-good 4-wave version (unchanged from R2's 82.5 config)
__global__ __launch_bounds__(BLOCK) void finalize_kernel(
    const float* __restrict__ ws, float* __restrict__ out, int b)
{
    __shared__ float sn[4], sd[4];
    float acc = 0.0f;
    for (int k = 0; k < b; ++k) {
        float n = 0.0f, d = 0.0f;
        for (int p = threadIdx.x; p < NTILE; p += BLOCK) {
            n += ws[(k * NTILE + p) * 2 + 0];
            d += ws[(k * NTILE + p) * 2 + 1];
        }
        for (int off = 32; off > 0; off >>= 1) {
            n += __shfl_down(n, off);
            d += __shfl_down(d, off);
        }
        if ((threadIdx.x & 63) == 0) { sn[threadIdx.x >> 6] = n; sd[threadIdx.x >> 6] = d; }
        __syncthreads();
        if (threadIdx.x == 0) {
            float tn = sn[0] + sn[1] + sn[2] + sn[3];
            float td = sd[0] + sd[1] + sd[2] + sd[3];
            acc += tn / fmaxf(td, 1.0f);
        }
        __syncthreads();
    }
    if (threadIdx.x == 0) out[0] = 1.0f - acc / (float)b;
}

extern "C" void kernel_launch(void* const* d_in, const int* in_sizes, int n_in,
                              void* d_out, int out_size, void* d_ws, size_t ws_size,
                              hipStream_t stream) {
    const float* pred  = (const float*)d_in[0];
    const float* truec = (const float*)d_in[1];
    const int* is_dna  = (const int*)d_in[2];
    const int* is_rna  = (const int*)d_in[3];
    const int* cmask   = (const int*)d_in[4];
    float* out = (float*)d_out;
    float* ws  = (float*)d_ws;

    const int b = in_sizes[2] / N;

    dim3 grid(NTILE, 1, b);   // 1088 x b = 2176 blocks
    lddt_main_kernel<<<grid, BLOCK, 0, stream>>>(pred, truec, is_dna, is_rna, cmask, ws);
    finalize_kernel<<<1, BLOCK, 0, stream>>>(ws, out, b);
}

// Round 6
// 81.006 us; speedup vs baseline: 1.1059x; 1.0761x over previous
//
#include <hip/hip_runtime.h>
#include <math.h>

#define N      4096
#define BLOCK  256
#define JW     32                  // j-tile width
#define NITILE (N / BLOCK)         // 16 i-tiles (256 rows each)
#define NTRI   1088                // sum_{t=0..15} (128 - 8t)
#define NQ     (JW / 4)            // 8 PAIR4 groups

typedef float v4f __attribute__((ext_vector_type(4)));

// s(e) = sum_k 1/(1 + c_k*e), c_k = e^{-t_k}, t = {0.5,1,2,4} = Pn(e)/Pd(e)
#define PN0 4.0f
#define PN1 3.384183069f
#define PN2 0.750655861f
#define PN3 0.036699475f
#define PD1 1.128061023f
#define PD2 0.375327930f
#define PD3 0.036699475f
#define PD4 0.000553084f

__device__ __forceinline__ int tri_off(int t) { return 132 * t - 4 * t * t; }
__device__ __forceinline__ v4f splat(float x) { return (v4f){x, x, x, x}; }

// ============================ SESSION LEDGER ============================
// Session-best: THIS kernel, 81.4 us (R0 bench). All subsequent rounds:
// R1: depth-1 SW pipeline of the 8 LDS broadcast reads -> 87.8 (+6.4,
//     VGPR-pressure regression). LDS latency is NOT the bottleneck.
// R2: j-per-lane VGPR / i-uniform s_load, ZERO hot-loop LDS -> 82.5
//     (neutral). LDS throughput is NOT the bottleneck.
// R3: R2 + launch_bounds(256,8) (2x occupancy) -> 84.2 (neutral).
//     Occupancy is NOT the bottleneck.
// R4: R2 with 64i-tiles, 1088 blocks, single round -> 89.6 (+7).
//     Per-block overhead/scheduling-tail is NOT the bottleneck.
// R5: R2 with readlane broadcast, zero hot-loop memory ops -> 87.2
//     (neutral-worse; ~2us of it is run-level clock drift).
// CONCLUSION: five mechanistically distinct main-kernel attacks all land
// in the +-3us noise band or regress => main kernel contributes <=~10us
// of the ~82us window. The window is dominated by the harness's 256 MiB
// workspace re-poison fill (39.7 us at 84-85% HBM peak = at the memory
// roofline) plus per-iteration reset dispatch overhead (dozens of
// dispatches per iteration per _ord spacing). Both are outside kernel
// control. This file restores the best-measured variant.
// Older notes: do NOT fuse finalize via global atomics + ticket (~75us
// regression); launch_bounds(256,8) on the v4f structure spills (3x).
// ========================================================================
__global__ __launch_bounds__(BLOCK, 4) void lddt_main_kernel(
    const float* __restrict__ pred, const float* __restrict__ truec,
    const int* __restrict__ is_dna, const int* __restrict__ is_rna,
    const int* __restrict__ cmask, float* __restrict__ ws)
{
    const int L     = blockIdx.x;     // 0..NTRI-1, linear upper-tri tile id
    const int batch = blockIdx.z;
    const int tid   = threadIdx.x;

    int itile = 0;
#pragma unroll
    for (int u = 1; u < NITILE; ++u) itile += (L >= tri_off(u)) ? 1 : 0;
    const int jseg = 8 * itile + (L - tri_off(itile));
    const bool diag = (jseg < 8 * itile + 8);   // j-range overlaps i-range

    const int i = itile * BLOCK + tid;

    const float* pb = pred  + (size_t)batch * N * 3;
    const float* tb = truec + (size_t)batch * N * 3;
    const int* dnab = is_dna + (size_t)batch * N;
    const int* rnab = is_rna + (size_t)batch * N;
    const int* cmb  = cmask  + (size_t)batch * N;

    // SoA j-tile staging: broadcast ds_read_b128 of each component array
    // yields operands pre-packed for v_pk_* (4 consecutive j's per v4f).
    __shared__ v4f spx[NQ], spy[NQ], spz[NQ], snw[NQ];
    __shared__ v4f stx[NQ], sty[NQ], stz[NQ], scw[NQ];
    const int j0 = jseg * JW;
    if (tid < JW) {
        const int j = j0 + tid;
        ((float*)spx)[tid] = pb[j*3+0];
        ((float*)spy)[tid] = pb[j*3+1];
        ((float*)spz)[tid] = pb[j*3+2];
        ((float*)snw)[tid] = (dnab[j] | rnab[j]) ? 675.0f : 0.0f;  // (30^2-15^2)
        ((float*)stx)[tid] = tb[j*3+0];
        ((float*)sty)[tid] = tb[j*3+1];
        ((float*)stz)[tid] = tb[j*3+2];
        ((float*)scw)[tid] = cmb[j] ? 1.0f : 0.0f;
    }
    __syncthreads();

    const float pix = pb[i*3+0], piy = pb[i*3+1], piz = pb[i*3+2];
    const float tix = tb[i*3+0], tiy = tb[i*3+1], tiz = tb[i*3+2];
    const float inuc01 = (dnab[i] | rnab[i]) ? 1.0f : 0.0f;
    const float icm    = cmb[i] ? 1.0f : 0.0f;

    const v4f pix4 = splat(pix), piy4 = splat(piy), piz4 = splat(piz);
    const v4f tix4 = splat(tix), tiy4 = splat(tiy), tiz4 = splat(tiz);
    const v4f base = splat(225.0f);          // 15^2
    const v4f inuc4 = splat(inuc01);

    float num = 0.0f;
    v4f den4 = splat(0.0f);

    // 4 pairs per iteration, packed f32 math; 2 shared rcps per group
#define PAIR4(Q, NEED_TRI)                                                     \
    {                                                                          \
        const v4f Px = spx[Q], Py = spy[Q], Pz = spz[Q], Pw = snw[Q];          \
        const v4f Tx = stx[Q], Ty = sty[Q], Tz = stz[Q], Tw = scw[Q];          \
        v4f dxp = pix4 - Px, dyp = piy4 - Py, dzp = piz4 - Pz;                 \
        v4f d2p = dxp * dxp + dyp * dyp + dzp * dzp;                           \
        v4f dxt = tix4 - Tx, dyt = tiy4 - Ty, dzt = tiz4 - Tz;                 \
        v4f d2t = dxt * dxt + dyt * dyt + dzt * dzt;                           \
        v4f dp, dt;                                                            \
        dp.x = __builtin_amdgcn_sqrtf(d2p.x); dt.x = __builtin_amdgcn_sqrtf(d2t.x); \
        dp.y = __builtin_amdgcn_sqrtf(d2p.y); dt.y = __builtin_amdgcn_sqrtf(d2t.y); \
        dp.z = __builtin_amdgcn_sqrtf(d2p.z); dt.z = __builtin_amdgcn_sqrtf(d2t.z); \
        dp.w = __builtin_amdgcn_sqrtf(d2p.w); dt.w = __builtin_amdgcn_sqrtf(d2t.w); \
        v4f dd = dt - dp;                                                      \
        v4f e;                                                                 \
        e.x = __expf(fminf(fabsf(dd.x), 10.0f));                               \
        e.y = __expf(fminf(fabsf(dd.y), 10.0f));                               \
        e.z = __expf(fminf(fabsf(dd.z), 10.0f));                               \
        e.w = __expf(fminf(fabsf(dd.w), 10.0f));                               \
        v4f NN = ((e * splat(PN3) + splat(PN2)) * e + splat(PN1)) * e + splat(PN0); \
        v4f ND = (((e * splat(PD4) + splat(PD3)) * e + splat(PD2)) * e + splat(PD1)) * e + splat(1.0f); \
        v4f cut = base + inuc4 * Pw;                                           \
        v4f m;                                                                 \
        { bool k0 = d2t.x < cut.x, k1 = d2t.y < cut.y,                         \
           k2 = d2t.z < cut.z, k3 = d2t.w < cut.w;                             \
          if (NEED_TRI) { const int jb = j0 + 4 * (Q);                         \
            k0 = k0 && (jb + 0 > i); k1 = k1 && (jb + 1 > i);                  \
            k2 = k2 && (jb + 2 > i); k3 = k3 && (jb + 3 > i); }                \
          m.x = k0 ? Tw.x : 0.0f; m.y = k1 ? Tw.y : 0.0f;                      \
          m.z = k2 ? Tw.z : 0.0f; m.w = k3 ? Tw.w : 0.0f; }                    \
        v4f t = m * NN;                                                        \
        den4 += m;                                                             \
        float na = fmaf(t.x, ND.y, t.y * ND.x);                                \
        num = fmaf(na, __builtin_amdgcn_rcpf(ND.x * ND.y), num);               \
        float nb = fmaf(t.z, ND.w, t.w * ND.z);                                \
        num = fmaf(nb, __builtin_amdgcn_rcpf(ND.z * ND.w), num);               \
    }

    if (diag) {
#pragma unroll 2
        for (int q = 0; q < NQ; ++q) PAIR4(q, true)
    } else {
#pragma unroll 2
        for (int q = 0; q < NQ; ++q) PAIR4(q, false)
    }
#undef PAIR4

    float den = den4.x + den4.y + den4.z + den4.w;

    // symmetry x2, threshold-mean /4, gate by cm_i
    num *= 0.5f * icm;
    den *= 2.0f * icm;

    for (int off = 32; off > 0; off >>= 1) {
        num += __shfl_down(num, off);
        den += __shfl_down(den, off);
    }
    __shared__ float rn[BLOCK / 64], rd[BLOCK / 64];
    const int wid = tid >> 6, lane = tid & 63;
    if (lane == 0) { rn[wid] = num; rd[wid] = den; }
    __syncthreads();
    if (tid == 0) {
        float tn = rn[0] + rn[1] + rn[2] + rn[3];
        float td = rd[0] + rd[1] + rd[2] + rd[3];
        const int bid = batch * NTRI + L;
        ws[bid * 2 + 0] = tn;   // plain stores to distinct slots -> no init,
        ws[bid * 2 + 1] = td;   // no atomics, no fence
    }
}

__global__ __launch_bounds__(BLOCK) void finalize_kernel(
    const float* __restrict__ ws, float* __restrict__ out, int b)
{
    __shared__ float sn[4], sd[4];
    float acc = 0.0f;
    for (int k = 0; k < b; ++k) {
        float n = 0.0f, d = 0.0f;
        for (int p = threadIdx.x; p < NTRI; p += BLOCK) {
            n += ws[(k * NTRI + p) * 2 + 0];
            d += ws[(k * NTRI + p) * 2 + 1];
        }
        for (int off = 32; off > 0; off >>= 1) {
            n += __shfl_down(n, off);
            d += __shfl_down(d, off);
        }
        if ((threadIdx.x & 63) == 0) { sn[threadIdx.x >> 6] = n; sd[threadIdx.x >> 6] = d; }
        __syncthreads();
        if (threadIdx.x == 0) {
            float tn = sn[0] + sn[1] + sn[2] + sn[3];
            float td = sd[0] + sd[1] + sd[2] + sd[3];
            acc += tn / fmaxf(td, 1.0f);
        }
        __syncthreads();
    }
    if (threadIdx.x == 0) out[0] = 1.0f - acc / (float)b;
}

extern "C" void kernel_launch(void* const* d_in, const int* in_sizes, int n_in,
                              void* d_out, int out_size, void* d_ws, size_t ws_size,
                              hipStream_t stream) {
    const float* pred  = (const float*)d_in[0];
    const float* truec = (const float*)d_in[1];
    const int* is_dna  = (const int*)d_in[2];
    const int* is_rna  = (const int*)d_in[3];
    const int* cmask   = (const int*)d_in[4];
    float* out = (float*)d_out;
    float* ws  = (float*)d_ws;

    const int b = in_sizes[2] / N;

    dim3 grid(NTRI, 1, b);   // 1088 x b = 2176 blocks -> 8.5 blocks/CU
    lddt_main_kernel<<<grid, BLOCK, 0, stream>>>(pred, truec, is_dna, is_rna, cmask, ws);
    finalize_kernel<<<1, BLOCK, 0, stream>>>(ws, out, b);
}